// Round 10
// baseline (254.179 us; speedup 1.0000x reference)
//
#include <hip/hip_runtime.h>
#include <cstdint>
#include <cstddef>

// ---- types ----
typedef unsigned short u16;
typedef float  f32x4  __attribute__((ext_vector_type(4)));
typedef __bf16 bf16x8 __attribute__((ext_vector_type(8)));
typedef unsigned short us8 __attribute__((ext_vector_type(8)));
typedef unsigned short us4 __attribute__((ext_vector_type(4)));
typedef float  f32x4v __attribute__((ext_vector_type(4)));
typedef unsigned int u32x2 __attribute__((ext_vector_type(2)));

#define AS1 __attribute__((address_space(1)))
#define AS3 __attribute__((address_space(3)))

// fp32 -> bf16 round-to-nearest-even (scalar)
__device__ __forceinline__ u16 f2b(float f) {
  unsigned u = __float_as_uint(f);
  u += 0x7FFFu + ((u >> 16) & 1u);
  return (u16)(u >> 16);
}

// pack two fp32 -> bf16x2 dword (round-half-up; a = low 16, b = high 16)
__device__ __forceinline__ unsigned pkbf(float a, float b) {
  unsigned ua = __float_as_uint(a) + 0x8000u;
  unsigned ub = __float_as_uint(b) + 0x8000u;
  return __builtin_amdgcn_perm(ub, ua, 0x07060302u);
}

// pack two fp32 -> bf16x2 via casts (compiler emits v_cvt_pk_bf16_f32, RNE)
__device__ __forceinline__ unsigned cvtpk(float a, float b) {
  unsigned short lo = __builtin_bit_cast(unsigned short, (__bf16)a);
  unsigned short hi = __builtin_bit_cast(unsigned short, (__bf16)b);
  return (unsigned)lo | ((unsigned)hi << 16);
}

__device__ __forceinline__ bf16x8 ldfrag(const u16* p) {
  us8 v = *(const us8*)p;
  return __builtin_bit_cast(bf16x8, v);
}

__device__ __forceinline__ f32x4 mfma16(bf16x8 a, bf16x8 b, f32x4 c) {
  return __builtin_amdgcn_mfma_f32_16x16x32_bf16(a, b, c, 0, 0, 0);
}

// async global->LDS, 16B per lane; lds base must be wave-uniform (lane*16 auto-added)
__device__ __forceinline__ void gl_lds16(const u16* g, AS3 u16* l) {
  __builtin_amdgcn_global_load_lds((AS1 void*)g, (AS3 void*)l, 16, 0, 0);
}

#define SBAR0() __builtin_amdgcn_sched_barrier(0)
#define WVM0()  do { __asm__ volatile("s_waitcnt vmcnt(0)" ::: "memory"); SBAR0(); } while (0)

// R13 BK=64 LDS layout: rows of 64 u16 = eight 16B granules; row stride 128B
// = exactly 32 banks, so bank depends only on granule position. Swizzle:
//   LDS[row r][pos p] = global[r][g], p = g ^ (r&7)
// Staging (linear dest, global_load_lds): source granule g = (lane&7)^(lane>>3).
// Reader frag (row R, kchunk kk, quad): pos = (kk*4+quad) ^ (R&7), R&7=l16&7.
// Every 8 consecutive lanes covers pos 0..7 bijectively -> ~0 conflicts.

// ---- fused cast: x + all 4 weights. grid-stride, 3072 blocks x 4 iters ----
__global__ __launch_bounds__(256) void cvt_all(
    const float* __restrict__ x,
    const float* __restrict__ Wq, const float* __restrict__ Wk,
    const float* __restrict__ Wv, const float* __restrict__ Wo,
    u16* __restrict__ xb, u16* __restrict__ Wqkv, u16* __restrict__ Wob) {
  for (int blk = blockIdx.x; blk < 12288; blk += 3072) {
    const float* s;
    u16* d;
    int i;
    if (blk < 8192)       { s = x;  d = xb;             i = blk * 256 + threadIdx.x; }
    else if (blk < 9216)  { s = Wq; d = Wqkv;           i = (blk - 8192) * 256 + threadIdx.x; }
    else if (blk < 10240) { s = Wk; d = Wqkv + 1048576; i = (blk - 9216) * 256 + threadIdx.x; }
    else if (blk < 11264) { s = Wv; d = Wqkv + 2097152; i = (blk - 10240) * 256 + threadIdx.x; }
    else                  { s = Wo; d = Wob;            i = (blk - 11264) * 256 + threadIdx.x; }
    f32x4v f = ((const f32x4v*)s)[i];
    us4 o = { f2b(f[0]), f2b(f[1]), f2b(f[2]), f2b(f[3]) };
    ((us4*)d)[i] = o;
  }
}

// ---- GEMM1: C = X @ Wqkv^T -> Q (prescaled by 0.125*log2e), K, Vt.
// 128x128 tile, 256 threads, BK=64 (R13), per-section MFMA orientation +
// 8B packed epilogue (R12), persistent 512-block grid + same-A sec fusion +
// XCD-chunk swizzle (R15).
// R16: T3-min 2-phase double-buffered K-loop — 48 linear K-tiles (3 secs x
// 16), STAGE(T+1 -> buf^1) issued BEFORE compute(buf), one vmcnt(0)+barrier
// per tile (was 2 barriers + serial drain). The pipeline never drains across
// sec boundaries (tile 16*s is staged at T=16*s-1); epilogues overlap the
// next sec's first loads. LDS 64 KB (2 blocks/CU preserved, = VGPR cap).
__global__ __launch_bounds__(256) void gemm_qkv(
    const u16* __restrict__ A, const u16* __restrict__ W,
    u16* __restrict__ Qb, u16* __restrict__ Kb, u16* __restrict__ Vt) {
  __shared__ u16 lA[2 * 128 * 64];   // 32 KB (2 buffers)
  __shared__ u16 lB[2 * 128 * 64];   // 32 KB
  const int tid = threadIdx.x;
  const int lane = tid & 63, wave = tid >> 6;
  const int quad = lane >> 4, l16 = lane & 15;
  const int wr = wave >> 1, wc = wave & 1;

  const int p = blockIdx.x;
  const int l = (p & 7) * 64 + (p >> 3);   // XCD-chunk swizzle (bijective)
  const int by = l >> 3;
  const int bx0 = l & 7;
  const int m0 = by * 128;

  AS3 u16* lA3 = (AS3 u16*)lA;
  AS3 u16* lB3 = (AS3 u16*)lB;
  const int g3 = (((lane & 7) ^ (lane >> 3)) * 8);   // staging source granule col
  const int srow = lane >> 3;                        // 0..7 within 8-row group
  const int pA = ((quad) ^ (l16 & 7)) * 8;           // reader pos, kk=0
  const int pB = ((4 + quad) ^ (l16 & 7)) * 8;       // reader pos, kk=1

  const u16* gA = A + (size_t)(m0 + wave * 8 + srow) * 1024 + g3;
  const u16* gW = W + (size_t)(wave * 8 + srow) * 1024 + g3;  // + tile-row offset per T

  // stage K-tile T into buffer T&1 (sec = T>>4, k0 = (T&15)*64)
#define STAGE_T(T) do {                                                     \
    int sec_ = (T) >> 4;                                                    \
    int k0_ = ((T) & 15) * 64;                                              \
    int bo_ = ((T) & 1) * 8192;                                             \
    const u16* gBp_ = gW + (size_t)((bx0 + sec_ * 8) * 128) * 1024 + k0_;   \
    const u16* gAp_ = gA + k0_;                                             \
    _Pragma("unroll") for (int i_ = 0; i_ < 4; i_++) {                      \
      gl_lds16(gAp_ + (size_t)i_ * 32768, lA3 + bo_ + (i_ * 4 + wave) * 512); \
      gl_lds16(gBp_ + (size_t)i_ * 32768, lB3 + bo_ + (i_ * 4 + wave) * 512); \
    }                                                                       \
    SBAR0();                                                                \
  } while (0)

  f32x4 acc[4][4] = {};

  STAGE_T(0);
  WVM0();
  __builtin_amdgcn_s_barrier();
  SBAR0();

#pragma unroll 1
  for (int T = 0; T < 48; T++) {
    if (T < 47) STAGE_T(T + 1);          // loads fly under this tile's compute
    const int sec = T >> 4;
    const u16* bA = lA + (T & 1) * 8192;
    const u16* bB = lB + (T & 1) * 8192;
#pragma unroll
    for (int kk = 0; kk < 2; kk++) {
      const int pk = kk ? pB : pA;
      bf16x8 aF[4], bF[4];
#pragma unroll
      for (int mt = 0; mt < 4; mt++)
        aF[mt] = ldfrag(&bA[(wr * 64 + mt * 16 + l16) * 64 + pk]);
#pragma unroll
      for (int nt = 0; nt < 4; nt++)
        bF[nt] = ldfrag(&bB[(wc * 64 + nt * 16 + l16) * 64 + pk]);
      if (sec != 2) {  // SWAPPED: D[row=feature n, col=token m]
#pragma unroll
        for (int mt = 0; mt < 4; mt++)
#pragma unroll
          for (int nt = 0; nt < 4; nt++)
            acc[mt][nt] = mfma16(bF[nt], aF[mt], acc[mt][nt]);
      } else {         // NON-swapped: D[row=token m, col=feature n]
#pragma unroll
        for (int mt = 0; mt < 4; mt++)
#pragma unroll
          for (int nt = 0; nt < 4; nt++)
            acc[mt][nt] = mfma16(aF[mt], bF[nt], acc[mt][nt]);
      }
    }
    WVM0();                               // next tile landed (cheap: overlapped)
    __builtin_amdgcn_s_barrier();         // all waves' stages visible
    SBAR0();

    if ((T & 15) == 15) {                 // sec epilogue; overlaps next sec's loads
      const int n0 = (bx0 + sec * 8) * 128;
      if (sec != 2) {
        const float qsc = (sec == 0) ? 0.180336880111120426f : 1.0f;  // 0.125*log2e
        u16* __restrict__ D = (sec == 0) ? Qb : Kb;
        const int hb = ((n0 & 1023) >> 6) + wc;
#pragma unroll
        for (int mt = 0; mt < 4; mt++) {
          int t = m0 + wr * 64 + mt * 16 + l16;
          int b = t >> 11, tt = t & 2047;
          size_t rowb = (((size_t)b * 16 + hb) * 2048 + tt) * 64;
#pragma unroll
          for (int nt = 0; nt < 4; nt++) {
            int e = nt * 16 + quad * 4;
            u32x2 pk = { pkbf(acc[mt][nt][0] * qsc, acc[mt][nt][1] * qsc),
                         pkbf(acc[mt][nt][2] * qsc, acc[mt][nt][3] * qsc) };
            *(u32x2*)&D[rowb + e] = pk;
          }
        }
      } else {
#pragma unroll
        for (int mt = 0; mt < 4; mt++) {
          int t = m0 + wr * 64 + mt * 16 + quad * 4;
          int b = t >> 11, tt = t & 2047;
#pragma unroll
          for (int nt = 0; nt < 4; nt++) {
            int ns = (n0 & 1023) + wc * 64 + nt * 16 + l16;
            int h = ns >> 6, e = ns & 63;
            size_t addr = (((size_t)b * 16 + h) * 64 + e) * 2048 + tt;
            u32x2 pk = { pkbf(acc[mt][nt][0], acc[mt][nt][1]),
                         pkbf(acc[mt][nt][2], acc[mt][nt][3]) };
            *(u32x2*)&Vt[addr] = pk;
          }
        }
      }
#pragma unroll
      for (int mt = 0; mt < 4; mt++)
#pragma unroll
        for (int nt = 0; nt < 4; nt++)
          acc[mt][nt] = (f32x4){0.f, 0.f, 0.f, 0.f};
    }
  }
#undef STAGE_T
}

// ---- flash attention v4: transposed S (A=K, B=Q); paired Q-tiles.
// grid (bh=64, pair=8), block 512 (8 waves).
// R14: max-free softmax (S bounded, exp2 domain); K/V via global_load_lds
// with XOR-granule swizzle; cvt_pk packing; l-sum on the MFMA pipe (R11).
__global__ __launch_bounds__(512, 4) void attn(
    const u16* __restrict__ Q, const u16* __restrict__ K,
    const u16* __restrict__ Vt, u16* __restrict__ O) {
  __shared__ u16 lK[128 * 64];     // [s][e-swz] 16 KB
  __shared__ u16 lV[64 * 128];     // [e][s-swz] 16 KB
  __shared__ u16 lP[8 * 16 * 40];  // per-wave [16t][32s, stride 40]
  const int tid = threadIdx.x;
  const int lane = tid & 63, wave = tid >> 6;
  const int quad = lane >> 4, l16 = lane & 15;
  const int bh = blockIdx.x;
  const int pidx = blockIdx.y;     // 0..7
  const size_t base = (size_t)bh * (2048 * 64);
  u16* lPw = lP + wave * 640;
  const int b = bh >> 4, h = bh & 15;
  AS3 u16* lK3 = (AS3 u16*)lK;
  AS3 u16* lV3 = (AS3 u16*)lV;

  // K staging: instr (wave,i): rows wave*16+i*8+(lane>>3), src granule
  // g=(lane&7)^(lane>>3); dest linear granule (wave*2+i)*64+lane.
  const int g3 = ((lane & 7) ^ (lane >> 3)) * 8;
  const u16* gK = K + base + (size_t)(wave * 16 + (lane >> 3)) * 64 + g3;
  // V staging: instr (wave,i): row e=wave*8+i*4+(lane>>4), src granule
  // g=(lane&15)^(e&7).
  const int er = lane >> 4, p16 = lane & 15;
  const int e0 = wave * 8 + er, e1 = wave * 8 + 4 + er;
  const u16* gV0 = Vt + base + (size_t)e0 * 2048 + ((p16 ^ (e0 & 7)) * 8);
  const u16* gV1 = Vt + base + (size_t)e1 * 2048 + ((p16 ^ (e1 & 7)) * 8);

  const int e7 = l16 & 7;
  const int pq0 = (quad ^ e7) * 8;        // K read pos, e-granule quad
  const int pq1 = ((4 + quad) ^ e7) * 8;  // K read pos, e-granule 4+quad

  // ones A-frag for the l-sum MFMA (bf16 1.0 = 0x3F80)
  us8 ones_u = { 0x3F80, 0x3F80, 0x3F80, 0x3F80, 0x3F80, 0x3F80, 0x3F80, 0x3F80 };
  const bf16x8 onesA = __builtin_bit_cast(bf16x8, ones_u);

  for (int half = 0; half < 2; half++) {
    const int qb = half ? pidx : (15 - pidx);   // long tile first
    const int t0 = qb << 7;
    const int tq = t0 + wave * 16 + l16;
    const bf16x8 qF0 = ldfrag(Q + base + (size_t)tq * 64 + quad * 8);
    const bf16x8 qF1 = ldfrag(Q + base + (size_t)tq * 64 + 32 + quad * 8);
    float l_i = 0.f;
    f32x4 o[4] = {};

    for (int j = 0; j <= qb; j++) {
      const int s0 = j << 7;
      __syncthreads();
      gl_lds16(gK + (size_t)s0 * 64,       lK3 + wave * 1024);
      gl_lds16(gK + (size_t)s0 * 64 + 512, lK3 + wave * 1024 + 512);
      gl_lds16(gV0 + s0, lV3 + wave * 1024);
      gl_lds16(gV1 + s0, lV3 + wave * 1024 + 512);
      __syncthreads();

      // S^T = K·Q^T : lane owns col t=tq, rows s = nt*16+quad*4+r
      f32x4 S[8];
      __builtin_amdgcn_s_setprio(1);
#pragma unroll
      for (int nt = 0; nt < 8; nt++) {
        int sr = nt * 16 + l16;
        f32x4 a = {};
        a = mfma16(ldfrag(&lK[sr * 64 + pq0]), qF0, a);
        a = mfma16(ldfrag(&lK[sr * 64 + pq1]), qF1, a);
        S[nt] = a;
      }
      __builtin_amdgcn_s_setprio(0);

      if (j == qb) {  // causal mask on diagonal tile
#pragma unroll
        for (int nt = 0; nt < 8; nt++)
#pragma unroll
          for (int r = 0; r < 4; r++) {
            int s = s0 + nt * 16 + quad * 4 + r;
            if (s > tq) S[nt][r] = -INFINITY;
          }
      }

      // shift-free softmax numerator: P = exp2(S) (S bounded; exp2(-inf)=0)
#pragma unroll
      for (int nt = 0; nt < 8; nt++)
#pragma unroll
        for (int r = 0; r < 4; r++)
          S[nt][r] = __builtin_amdgcn_exp2f(S[nt][r]);

      // PV per 32-wide s-chunk: P^T through wave-private LDS (in-order DS).
      // l-sum rides the MFMA pipe: ol = onesA · bP accumulated per chunk.
      f32x4 ol = {};
#pragma unroll
      for (int c = 0; c < 4; c++) {
        u32x2 d0 = { cvtpk(S[2*c][0],   S[2*c][1]),   cvtpk(S[2*c][2],   S[2*c][3]) };
        u32x2 d1 = { cvtpk(S[2*c+1][0], S[2*c+1][1]), cvtpk(S[2*c+1][2], S[2*c+1][3]) };
        *(u32x2*)&lPw[l16 * 40 + quad * 4]      = d0;  // s_local = quad*4+r
        *(u32x2*)&lPw[l16 * 40 + 16 + quad * 4] = d1;  // s_local = 16+quad*4+r
        __asm__ volatile("s_waitcnt lgkmcnt(0)" ::: "memory");
        bf16x8 bP = ldfrag(&lPw[l16 * 40 + quad * 8]);  // B-frag: n=t=l16, k=quad*8+j
        __builtin_amdgcn_s_setprio(1);
#pragma unroll
        for (int ot = 0; ot < 4; ot++) {
          int pos = ((c * 4 + quad) ^ e7) * 8;  // V read: s-granule c*4+quad
          o[ot] = mfma16(ldfrag(&lV[(ot * 16 + l16) * 128 + pos]), bP, o[ot]);
        }
        ol = mfma16(onesA, bP, ol);
        __builtin_amdgcn_s_setprio(0);
      }
      l_i += ol[0];
    }

    // O^T in C-layout: row e = ot*16+quad*4+r, col t = l16 -> per-lane 8B stores
    const float inv = 1.f / l_i;
#pragma unroll
    for (int ot = 0; ot < 4; ot++) {
      u32x2 pk = { cvtpk(o[ot][0] * inv, o[ot][1] * inv),
                   cvtpk(o[ot][2] * inv, o[ot][3] * inv) };
      *(u32x2*)&O[((size_t)b * 2048 + tq) * 1024 + h * 64 + ot * 16 + quad * 4] = pk;
    }
  }
}

// ---- GEMM2: out = Ao @ Wo^T + bo, fp32 epilogue. BK=64 (R13).
// R16: same 2-phase dbuf K-loop as gemm_qkv. grid (8, 64), block 256.
__global__ __launch_bounds__(256) void gemm_out(
    const u16* __restrict__ A, const u16* __restrict__ W,
    const float* __restrict__ bias, float* __restrict__ out) {
  __shared__ u16 lA[2 * 128 * 64];
  __shared__ u16 lB[2 * 128 * 64];
  const int tid = threadIdx.x;
  const int lane = tid & 63, wave = tid >> 6;
  const int quad = lane >> 4, l16 = lane & 15;
  const int wr = wave >> 1, wc = wave & 1;
  const int m0 = blockIdx.y * 128;
  const int n0 = blockIdx.x * 128;
  AS3 u16* lA3 = (AS3 u16*)lA;
  AS3 u16* lB3 = (AS3 u16*)lB;
  f32x4 acc[4][4] = {};
  const int g3 = (((lane & 7) ^ (lane >> 3)) * 8);
  const int srow = lane >> 3;
  const int pA = ((quad) ^ (l16 & 7)) * 8;
  const int pB = ((4 + quad) ^ (l16 & 7)) * 8;
  const u16* gA = A + (size_t)(m0 + wave * 8 + srow) * 1024 + g3;
  const u16* gB = W + (size_t)(n0 + wave * 8 + srow) * 1024 + g3;

#define STAGE_O(T) do {                                                     \
    int k0_ = (T) * 64;                                                     \
    int bo_ = ((T) & 1) * 8192;                                             \
    _Pragma("unroll") for (int i_ = 0; i_ < 4; i_++) {                      \
      gl_lds16(gA + (size_t)i_ * 32768 + k0_, lA3 + bo_ + (i_ * 4 + wave) * 512); \
      gl_lds16(gB + (size_t)i_ * 32768 + k0_, lB3 + bo_ + (i_ * 4 + wave) * 512); \
    }                                                                       \
    SBAR0();                                                                \
  } while (0)

  STAGE_O(0);
  WVM0();
  __builtin_amdgcn_s_barrier();
  SBAR0();

#pragma unroll 1
  for (int T = 0; T < 16; T++) {
    if (T < 15) STAGE_O(T + 1);
    const u16* bA = lA + (T & 1) * 8192;
    const u16* bB = lB + (T & 1) * 8192;
#pragma unroll
    for (int kk = 0; kk < 2; kk++) {
      const int pk = kk ? pB : pA;
      bf16x8 aF[4], bF[4];
#pragma unroll
      for (int mt = 0; mt < 4; mt++)
        aF[mt] = ldfrag(&bA[(wr * 64 + mt * 16 + l16) * 64 + pk]);
#pragma unroll
      for (int nt = 0; nt < 4; nt++)
        bF[nt] = ldfrag(&bB[(wc * 64 + nt * 16 + l16) * 64 + pk]);
#pragma unroll
      for (int mt = 0; mt < 4; mt++)
#pragma unroll
        for (int nt = 0; nt < 4; nt++)
          acc[mt][nt] = mfma16(aF[mt], bF[nt], acc[mt][nt]);
    }
    WVM0();
    __builtin_amdgcn_s_barrier();
    SBAR0();
  }
#undef STAGE_O

#pragma unroll
  for (int mt = 0; mt < 4; mt++) {
#pragma unroll
    for (int nt = 0; nt < 4; nt++) {
#pragma unroll
      for (int r = 0; r < 4; r++) {
        int m = m0 + wr * 64 + mt * 16 + quad * 4 + r;
        int n = n0 + wc * 64 + nt * 16 + l16;
        out[(size_t)m * 1024 + n] = acc[mt][nt][r] + bias[n];
      }
    }
  }
}

extern "C" void kernel_launch(void* const* d_in, const int* in_sizes, int n_in,
                              void* d_out, int out_size, void* d_ws, size_t ws_size,
                              hipStream_t stream) {
  const float* x  = (const float*)d_in[0];
  const float* Wq = (const float*)d_in[1];
  const float* Wk = (const float*)d_in[2];
  const float* Wv = (const float*)d_in[3];
  const float* Wo = (const float*)d_in[4];
  const float* bo = (const float*)d_in[5];
  float* out = (float*)d_out;

  // ws (u16 elems), 40 MB total: xb/Ao | Wqkv | Wob | Qb.
  // d_out doubles as scratch for Kb+Vt (dead before gemm_out's fp32 write).
  u16* ws   = (u16*)d_ws;
  u16* xb   = ws;
  u16* Wqkv = ws + 8388608;
  u16* Wob  = ws + 11534336;
  u16* Qb   = ws + 12582912;
  u16* Ao   = xb;                       // lifetime-disjoint reuse
  u16* Kb   = (u16*)d_out;
  u16* Vt   = Kb + 8388608;

  cvt_all<<<3072, 256, 0, stream>>>(x, Wq, Wk, Wv, Wo, xb, Wqkv, Wob);
  gemm_qkv<<<512, 256, 0, stream>>>(xb, Wqkv, Qb, Kb, Vt);
  attn<<<dim3(64, 8), 512, 0, stream>>>(Qb, Kb, Vt, Ao);
  gemm_out<<<dim3(8, 64), 256, 0, stream>>>(Ao, Wob, bo, out);
}

// Round 11
// 237.706 us; speedup vs baseline: 1.0693x; 1.0693x over previous
//
#include <hip/hip_runtime.h>
#include <cstdint>
#include <cstddef>

// ---- types ----
typedef unsigned short u16;
typedef float  f32x4  __attribute__((ext_vector_type(4)));
typedef __bf16 bf16x8 __attribute__((ext_vector_type(8)));
typedef unsigned short us8 __attribute__((ext_vector_type(8)));
typedef unsigned short us4 __attribute__((ext_vector_type(4)));
typedef float  f32x4v __attribute__((ext_vector_type(4)));
typedef unsigned int u32x2 __attribute__((ext_vector_type(2)));

#define AS1 __attribute__((address_space(1)))
#define AS3 __attribute__((address_space(3)))

// fp32 -> bf16 round-to-nearest-even (scalar)
__device__ __forceinline__ u16 f2b(float f) {
  unsigned u = __float_as_uint(f);
  u += 0x7FFFu + ((u >> 16) & 1u);
  return (u16)(u >> 16);
}

// pack two fp32 -> bf16x2 dword (round-half-up; a = low 16, b = high 16)
__device__ __forceinline__ unsigned pkbf(float a, float b) {
  unsigned ua = __float_as_uint(a) + 0x8000u;
  unsigned ub = __float_as_uint(b) + 0x8000u;
  return __builtin_amdgcn_perm(ub, ua, 0x07060302u);
}

// pack two fp32 -> bf16x2 via casts (compiler emits v_cvt_pk_bf16_f32, RNE)
__device__ __forceinline__ unsigned cvtpk(float a, float b) {
  unsigned short lo = __builtin_bit_cast(unsigned short, (__bf16)a);
  unsigned short hi = __builtin_bit_cast(unsigned short, (__bf16)b);
  return (unsigned)lo | ((unsigned)hi << 16);
}

__device__ __forceinline__ bf16x8 ldfrag(const u16* p) {
  us8 v = *(const us8*)p;
  return __builtin_bit_cast(bf16x8, v);
}

__device__ __forceinline__ f32x4 mfma16(bf16x8 a, bf16x8 b, f32x4 c) {
  return __builtin_amdgcn_mfma_f32_16x16x32_bf16(a, b, c, 0, 0, 0);
}

// async global->LDS, 16B per lane; lds base must be wave-uniform (lane*16 auto-added)
__device__ __forceinline__ void gl_lds16(const u16* g, AS3 u16* l) {
  __builtin_amdgcn_global_load_lds((AS1 void*)g, (AS3 void*)l, 16, 0, 0);
}

#define SBAR0() __builtin_amdgcn_sched_barrier(0)
#define WVMN(n) do { __asm__ volatile("s_waitcnt vmcnt(" #n ")" ::: "memory"); SBAR0(); } while (0)

// R13 BK=64 LDS layout: rows of 64 u16 = eight 16B granules; row stride 128B
// = exactly 32 banks, so bank depends only on granule position. Swizzle:
//   LDS[row r][pos p] = global[r][g], p = g ^ (r&7)
// Staging (linear dest, global_load_lds): source granule g = (lane&7)^(lane>>3).
// Reader frag (row R, kchunk kk, quad): pos = (kk*4+quad) ^ (R&7), R&7=l16&7.
// Every 8 consecutive lanes covers pos 0..7 bijectively -> ~0 conflicts.

// ---- fused cast: x + all 4 weights. grid-stride, 3072 blocks x 4 iters ----
__global__ __launch_bounds__(256) void cvt_all(
    const float* __restrict__ x,
    const float* __restrict__ Wq, const float* __restrict__ Wk,
    const float* __restrict__ Wv, const float* __restrict__ Wo,
    u16* __restrict__ xb, u16* __restrict__ Wqkv, u16* __restrict__ Wob) {
  for (int blk = blockIdx.x; blk < 12288; blk += 3072) {
    const float* s;
    u16* d;
    int i;
    if (blk < 8192)       { s = x;  d = xb;             i = blk * 256 + threadIdx.x; }
    else if (blk < 9216)  { s = Wq; d = Wqkv;           i = (blk - 8192) * 256 + threadIdx.x; }
    else if (blk < 10240) { s = Wk; d = Wqkv + 1048576; i = (blk - 9216) * 256 + threadIdx.x; }
    else if (blk < 11264) { s = Wv; d = Wqkv + 2097152; i = (blk - 10240) * 256 + threadIdx.x; }
    else                  { s = Wo; d = Wob;            i = (blk - 11264) * 256 + threadIdx.x; }
    f32x4v f = ((const f32x4v*)s)[i];
    us4 o = { f2b(f[0]), f2b(f[1]), f2b(f[2]), f2b(f[3]) };
    ((us4*)d)[i] = o;
  }
}

// ---- GEMM1: C = X @ Wqkv^T -> Q (prescaled by 0.125*log2e), K, Vt.
// 128x128 tile, 256 threads, BK=64 (R13), per-section MFMA orientation +
// 8B packed epilogue (R12), persistent 512-block grid + same-A sec fusion +
// XCD-chunk swizzle (R15).
// R17: counted-vmcnt double-buffer (T4, m218 pattern). Per tile:
//   STAGE(T+1 -> buf^1); vmcnt(8) [waits tile T only — T+1 stays in flight
//   the whole iteration]; barrier; compute(T); barrier.
// R16's fault: vmcnt(0) after compute drained the prefetch (250cy cover) and
// runtime-T address macros tripled VALU (36.7% busy). Fix: sec-outer/k0-inner
// loops, 3 precomputed B bases, induction-variable addressing. Sec-boundary
// prefetch keeps the pipe full across all 48 tiles; epilogues overlap loads.
__global__ __launch_bounds__(256) void gemm_qkv(
    const u16* __restrict__ A, const u16* __restrict__ W,
    u16* __restrict__ Qb, u16* __restrict__ Kb, u16* __restrict__ Vt) {
  __shared__ u16 lA[2 * 128 * 64];   // 32 KB (2 buffers)
  __shared__ u16 lB[2 * 128 * 64];   // 32 KB
  const int tid = threadIdx.x;
  const int lane = tid & 63, wave = tid >> 6;
  const int quad = lane >> 4, l16 = lane & 15;
  const int wr = wave >> 1, wc = wave & 1;

  const int p = blockIdx.x;
  const int l = (p & 7) * 64 + (p >> 3);   // XCD-chunk swizzle (bijective)
  const int by = l >> 3;
  const int bx0 = l & 7;
  const int m0 = by * 128;

  AS3 u16* lA3 = (AS3 u16*)lA;
  AS3 u16* lB3 = (AS3 u16*)lB;
  const int g3 = (((lane & 7) ^ (lane >> 3)) * 8);   // staging source granule col
  const int srow = lane >> 3;                        // 0..7 within 8-row group
  const int pA = ((quad) ^ (l16 & 7)) * 8;           // reader pos, kk=0
  const int pB = ((4 + quad) ^ (l16 & 7)) * 8;       // reader pos, kk=1

  const u16* gA  = A + (size_t)(m0 + wave * 8 + srow) * 1024 + g3;
  const u16* gB0 = W + (size_t)((bx0 * 128) + wave * 8 + srow) * 1024 + g3;
  const u16* gB1 = gB0 + (size_t)1024 * 1024;   // +8*128 rows
  const u16* gB2 = gB1 + (size_t)1024 * 1024;

#define STAGE(pa, pb, bo) do {                                              \
    _Pragma("unroll") for (int i_ = 0; i_ < 4; i_++) {                      \
      gl_lds16((pa) + (size_t)i_ * 32768, lA3 + (bo) + (i_ * 4 + wave) * 512); \
      gl_lds16((pb) + (size_t)i_ * 32768, lB3 + (bo) + (i_ * 4 + wave) * 512); \
    }                                                                       \
    SBAR0();                                                                \
  } while (0)

  f32x4 acc[4][4] = {};
  STAGE(gA, gB0, 0);                  // tile 0 in flight; no wait yet

#pragma unroll 1
  for (int sec = 0; sec < 3; sec++) {
    const u16* gB  = (sec == 0) ? gB0 : (sec == 1) ? gB1 : gB2;
    const u16* gBn = (sec == 0) ? gB1 : gB2;   // next sec's base (unused at sec 2)

#pragma unroll 1
    for (int k0 = 0; k0 < 1024; k0 += 64) {
      const int bo = ((k0 >> 6) & 1) * 8192;
      if (k0 < 960) {
        STAGE(gA + k0 + 64, gB + k0 + 64, bo ^ 8192);
        WVMN(8);                      // tile T landed; T+1 stays in flight
      } else if (sec < 2) {
        STAGE(gA, gBn, bo ^ 8192);    // next sec's tile 0
        WVMN(8);
      } else {
        WVMN(0);                      // final tile: drain
      }
      __builtin_amdgcn_s_barrier();   // tile T visible to all waves
      SBAR0();

      const u16* bA = lA + bo;
      const u16* bB = lB + bo;
#pragma unroll
      for (int kk = 0; kk < 2; kk++) {
        const int pk = kk ? pB : pA;
        bf16x8 aF[4], bF[4];
#pragma unroll
        for (int mt = 0; mt < 4; mt++)
          aF[mt] = ldfrag(&bA[(wr * 64 + mt * 16 + l16) * 64 + pk]);
#pragma unroll
        for (int nt = 0; nt < 4; nt++)
          bF[nt] = ldfrag(&bB[(wc * 64 + nt * 16 + l16) * 64 + pk]);
        if (sec != 2) {  // SWAPPED: D[row=feature n, col=token m]
#pragma unroll
          for (int mt = 0; mt < 4; mt++)
#pragma unroll
            for (int nt = 0; nt < 4; nt++)
              acc[mt][nt] = mfma16(bF[nt], aF[mt], acc[mt][nt]);
        } else {         // NON-swapped: D[row=token m, col=feature n]
#pragma unroll
          for (int mt = 0; mt < 4; mt++)
#pragma unroll
            for (int nt = 0; nt < 4; nt++)
              acc[mt][nt] = mfma16(aF[mt], bF[nt], acc[mt][nt]);
        }
      }
      __builtin_amdgcn_s_barrier();   // all reads of buf done before its rewrite
      SBAR0();
    }

    // sec epilogue (per-wave regs only; overlaps next sec's in-flight loads)
    const int n0 = (bx0 + sec * 8) * 128;
    if (sec != 2) {
      const float qsc = (sec == 0) ? 0.180336880111120426f : 1.0f;  // 0.125*log2e
      u16* __restrict__ D = (sec == 0) ? Qb : Kb;
      const int hb = ((n0 & 1023) >> 6) + wc;
#pragma unroll
      for (int mt = 0; mt < 4; mt++) {
        int t = m0 + wr * 64 + mt * 16 + l16;
        int b = t >> 11, tt = t & 2047;
        size_t rowb = (((size_t)b * 16 + hb) * 2048 + tt) * 64;
#pragma unroll
        for (int nt = 0; nt < 4; nt++) {
          int e = nt * 16 + quad * 4;
          u32x2 pk = { pkbf(acc[mt][nt][0] * qsc, acc[mt][nt][1] * qsc),
                       pkbf(acc[mt][nt][2] * qsc, acc[mt][nt][3] * qsc) };
          *(u32x2*)&D[rowb + e] = pk;
        }
      }
    } else {
#pragma unroll
      for (int mt = 0; mt < 4; mt++) {
        int t = m0 + wr * 64 + mt * 16 + quad * 4;
        int b = t >> 11, tt = t & 2047;
#pragma unroll
        for (int nt = 0; nt < 4; nt++) {
          int ns = (n0 & 1023) + wc * 64 + nt * 16 + l16;
          int h = ns >> 6, e = ns & 63;
          size_t addr = (((size_t)b * 16 + h) * 64 + e) * 2048 + tt;
          u32x2 pk = { pkbf(acc[mt][nt][0], acc[mt][nt][1]),
                       pkbf(acc[mt][nt][2], acc[mt][nt][3]) };
          *(u32x2*)&Vt[addr] = pk;
        }
      }
    }
#pragma unroll
    for (int mt = 0; mt < 4; mt++)
#pragma unroll
      for (int nt = 0; nt < 4; nt++)
        acc[mt][nt] = (f32x4){0.f, 0.f, 0.f, 0.f};
  }
#undef STAGE
}

// ---- flash attention v4: transposed S (A=K, B=Q); paired Q-tiles.
// grid (bh=64, pair=8), block 512 (8 waves).
// R14: max-free softmax (S bounded, exp2 domain); K/V via global_load_lds
// with XOR-granule swizzle; cvt_pk packing; l-sum on the MFMA pipe (R11).
__global__ __launch_bounds__(512, 4) void attn(
    const u16* __restrict__ Q, const u16* __restrict__ K,
    const u16* __restrict__ Vt, u16* __restrict__ O) {
  __shared__ u16 lK[128 * 64];     // [s][e-swz] 16 KB
  __shared__ u16 lV[64 * 128];     // [e][s-swz] 16 KB
  __shared__ u16 lP[8 * 16 * 40];  // per-wave [16t][32s, stride 40]
  const int tid = threadIdx.x;
  const int lane = tid & 63, wave = tid >> 6;
  const int quad = lane >> 4, l16 = lane & 15;
  const int bh = blockIdx.x;
  const int pidx = blockIdx.y;     // 0..7
  const size_t base = (size_t)bh * (2048 * 64);
  u16* lPw = lP + wave * 640;
  const int b = bh >> 4, h = bh & 15;
  AS3 u16* lK3 = (AS3 u16*)lK;
  AS3 u16* lV3 = (AS3 u16*)lV;

  // K staging: instr (wave,i): rows wave*16+i*8+(lane>>3), src granule
  // g=(lane&7)^(lane>>3); dest linear granule (wave*2+i)*64+lane.
  const int g3 = ((lane & 7) ^ (lane >> 3)) * 8;
  const u16* gK = K + base + (size_t)(wave * 16 + (lane >> 3)) * 64 + g3;
  // V staging: instr (wave,i): row e=wave*8+i*4+(lane>>4), src granule
  // g=(lane&15)^(e&7).
  const int er = lane >> 4, p16 = lane & 15;
  const int e0 = wave * 8 + er, e1 = wave * 8 + 4 + er;
  const u16* gV0 = Vt + base + (size_t)e0 * 2048 + ((p16 ^ (e0 & 7)) * 8);
  const u16* gV1 = Vt + base + (size_t)e1 * 2048 + ((p16 ^ (e1 & 7)) * 8);

  const int e7 = l16 & 7;
  const int pq0 = (quad ^ e7) * 8;        // K read pos, e-granule quad
  const int pq1 = ((4 + quad) ^ e7) * 8;  // K read pos, e-granule 4+quad

  // ones A-frag for the l-sum MFMA (bf16 1.0 = 0x3F80)
  us8 ones_u = { 0x3F80, 0x3F80, 0x3F80, 0x3F80, 0x3F80, 0x3F80, 0x3F80, 0x3F80 };
  const bf16x8 onesA = __builtin_bit_cast(bf16x8, ones_u);

  for (int half = 0; half < 2; half++) {
    const int qb = half ? pidx : (15 - pidx);   // long tile first
    const int t0 = qb << 7;
    const int tq = t0 + wave * 16 + l16;
    const bf16x8 qF0 = ldfrag(Q + base + (size_t)tq * 64 + quad * 8);
    const bf16x8 qF1 = ldfrag(Q + base + (size_t)tq * 64 + 32 + quad * 8);
    float l_i = 0.f;
    f32x4 o[4] = {};

    for (int j = 0; j <= qb; j++) {
      const int s0 = j << 7;
      __syncthreads();
      gl_lds16(gK + (size_t)s0 * 64,       lK3 + wave * 1024);
      gl_lds16(gK + (size_t)s0 * 64 + 512, lK3 + wave * 1024 + 512);
      gl_lds16(gV0 + s0, lV3 + wave * 1024);
      gl_lds16(gV1 + s0, lV3 + wave * 1024 + 512);
      __syncthreads();

      // S^T = K·Q^T : lane owns col t=tq, rows s = nt*16+quad*4+r
      f32x4 S[8];
      __builtin_amdgcn_s_setprio(1);
#pragma unroll
      for (int nt = 0; nt < 8; nt++) {
        int sr = nt * 16 + l16;
        f32x4 a = {};
        a = mfma16(ldfrag(&lK[sr * 64 + pq0]), qF0, a);
        a = mfma16(ldfrag(&lK[sr * 64 + pq1]), qF1, a);
        S[nt] = a;
      }
      __builtin_amdgcn_s_setprio(0);

      if (j == qb) {  // causal mask on diagonal tile
#pragma unroll
        for (int nt = 0; nt < 8; nt++)
#pragma unroll
          for (int r = 0; r < 4; r++) {
            int s = s0 + nt * 16 + quad * 4 + r;
            if (s > tq) S[nt][r] = -INFINITY;
          }
      }

      // shift-free softmax numerator: P = exp2(S) (S bounded; exp2(-inf)=0)
#pragma unroll
      for (int nt = 0; nt < 8; nt++)
#pragma unroll
        for (int r = 0; r < 4; r++)
          S[nt][r] = __builtin_amdgcn_exp2f(S[nt][r]);

      // PV per 32-wide s-chunk: P^T through wave-private LDS (in-order DS).
      // l-sum rides the MFMA pipe: ol = onesA · bP accumulated per chunk.
      f32x4 ol = {};
#pragma unroll
      for (int c = 0; c < 4; c++) {
        u32x2 d0 = { cvtpk(S[2*c][0],   S[2*c][1]),   cvtpk(S[2*c][2],   S[2*c][3]) };
        u32x2 d1 = { cvtpk(S[2*c+1][0], S[2*c+1][1]), cvtpk(S[2*c+1][2], S[2*c+1][3]) };
        *(u32x2*)&lPw[l16 * 40 + quad * 4]      = d0;  // s_local = quad*4+r
        *(u32x2*)&lPw[l16 * 40 + 16 + quad * 4] = d1;  // s_local = 16+quad*4+r
        __asm__ volatile("s_waitcnt lgkmcnt(0)" ::: "memory");
        bf16x8 bP = ldfrag(&lPw[l16 * 40 + quad * 8]);  // B-frag: n=t=l16, k=quad*8+j
        __builtin_amdgcn_s_setprio(1);
#pragma unroll
        for (int ot = 0; ot < 4; ot++) {
          int pos = ((c * 4 + quad) ^ e7) * 8;  // V read: s-granule c*4+quad
          o[ot] = mfma16(ldfrag(&lV[(ot * 16 + l16) * 128 + pos]), bP, o[ot]);
        }
        ol = mfma16(onesA, bP, ol);
        __builtin_amdgcn_s_setprio(0);
      }
      l_i += ol[0];
    }

    // O^T in C-layout: row e = ot*16+quad*4+r, col t = l16 -> per-lane 8B stores
    const float inv = 1.f / l_i;
#pragma unroll
    for (int ot = 0; ot < 4; ot++) {
      u32x2 pk = { cvtpk(o[ot][0] * inv, o[ot][1] * inv),
                   cvtpk(o[ot][2] * inv, o[ot][3] * inv) };
      *(u32x2*)&O[((size_t)b * 2048 + tq) * 1024 + h * 64 + ot * 16 + quad * 4] = pk;
    }
  }
}

// ---- GEMM2: out = Ao @ Wo^T + bo, fp32 epilogue. BK=64 (R13).
// R17: counted-vmcnt dbuf (same pattern as gemm_qkv). grid (8, 64), block 256.
__global__ __launch_bounds__(256) void gemm_out(
    const u16* __restrict__ A, const u16* __restrict__ W,
    const float* __restrict__ bias, float* __restrict__ out) {
  __shared__ u16 lA[2 * 128 * 64];
  __shared__ u16 lB[2 * 128 * 64];
  const int tid = threadIdx.x;
  const int lane = tid & 63, wave = tid >> 6;
  const int quad = lane >> 4, l16 = lane & 15;
  const int wr = wave >> 1, wc = wave & 1;
  const int m0 = blockIdx.y * 128;
  const int n0 = blockIdx.x * 128;
  AS3 u16* lA3 = (AS3 u16*)lA;
  AS3 u16* lB3 = (AS3 u16*)lB;
  f32x4 acc[4][4] = {};
  const int g3 = (((lane & 7) ^ (lane >> 3)) * 8);
  const int srow = lane >> 3;
  const int pA = ((quad) ^ (l16 & 7)) * 8;
  const int pB = ((4 + quad) ^ (l16 & 7)) * 8;
  const u16* gA = A + (size_t)(m0 + wave * 8 + srow) * 1024 + g3;
  const u16* gB = W + (size_t)(n0 + wave * 8 + srow) * 1024 + g3;

#define STAGE_O(k0v, bo) do {                                               \
    _Pragma("unroll") for (int i_ = 0; i_ < 4; i_++) {                      \
      gl_lds16(gA + (size_t)i_ * 32768 + (k0v), lA3 + (bo) + (i_ * 4 + wave) * 512); \
      gl_lds16(gB + (size_t)i_ * 32768 + (k0v), lB3 + (bo) + (i_ * 4 + wave) * 512); \
    }                                                                       \
    SBAR0();                                                                \
  } while (0)

  STAGE_O(0, 0);

#pragma unroll 1
  for (int k0 = 0; k0 < 1024; k0 += 64) {
    const int bo = ((k0 >> 6) & 1) * 8192;
    if (k0 < 960) {
      STAGE_O(k0 + 64, bo ^ 8192);
      WVMN(8);
    } else {
      WVMN(0);
    }
    __builtin_amdgcn_s_barrier();
    SBAR0();
    const u16* bA = lA + bo;
    const u16* bB = lB + bo;
#pragma unroll
    for (int kk = 0; kk < 2; kk++) {
      const int pk = kk ? pB : pA;
      bf16x8 aF[4], bF[4];
#pragma unroll
      for (int mt = 0; mt < 4; mt++)
        aF[mt] = ldfrag(&bA[(wr * 64 + mt * 16 + l16) * 64 + pk]);
#pragma unroll
      for (int nt = 0; nt < 4; nt++)
        bF[nt] = ldfrag(&bB[(wc * 64 + nt * 16 + l16) * 64 + pk]);
#pragma unroll
      for (int mt = 0; mt < 4; mt++)
#pragma unroll
        for (int nt = 0; nt < 4; nt++)
          acc[mt][nt] = mfma16(aF[mt], bF[nt], acc[mt][nt]);
    }
    __builtin_amdgcn_s_barrier();
    SBAR0();
  }
#undef STAGE_O

#pragma unroll
  for (int mt = 0; mt < 4; mt++) {
#pragma unroll
    for (int nt = 0; nt < 4; nt++) {
#pragma unroll
      for (int r = 0; r < 4; r++) {
        int m = m0 + wr * 64 + mt * 16 + quad * 4 + r;
        int n = n0 + wc * 64 + nt * 16 + l16;
        out[(size_t)m * 1024 + n] = acc[mt][nt][r] + bias[n];
      }
    }
  }
}

extern "C" void kernel_launch(void* const* d_in, const int* in_sizes, int n_in,
                              void* d_out, int out_size, void* d_ws, size_t ws_size,
                              hipStream_t stream) {
  const float* x  = (const float*)d_in[0];
  const float* Wq = (const float*)d_in[1];
  const float* Wk = (const float*)d_in[2];
  const float* Wv = (const float*)d_in[3];
  const float* Wo = (const float*)d_in[4];
  const float* bo = (const float*)d_in[5];
  float* out = (float*)d_out;

  // ws (u16 elems), 40 MB total: xb/Ao | Wqkv | Wob | Qb.
  // d_out doubles as scratch for Kb+Vt (dead before gemm_out's fp32 write).
  u16* ws   = (u16*)d_ws;
  u16* xb   = ws;
  u16* Wqkv = ws + 8388608;
  u16* Wob  = ws + 11534336;
  u16* Qb   = ws + 12582912;
  u16* Ao   = xb;                       // lifetime-disjoint reuse
  u16* Kb   = (u16*)d_out;
  u16* Vt   = Kb + 8388608;

  cvt_all<<<3072, 256, 0, stream>>>(x, Wq, Wk, Wv, Wo, xb, Wqkv, Wob);
  gemm_qkv<<<512, 256, 0, stream>>>(xb, Wqkv, Qb, Kb, Vt);
  attn<<<dim3(64, 8), 512, 0, stream>>>(Qb, Kb, Vt, Ao);
  gemm_out<<<dim3(8, 64), 256, 0, stream>>>(Ao, Wob, bo, out);
}

// Round 12
// 237.255 us; speedup vs baseline: 1.0713x; 1.0019x over previous
//
#include <hip/hip_runtime.h>
#include <cstdint>
#include <cstddef>

// ---- types ----
typedef unsigned short u16;
typedef float  f32x4  __attribute__((ext_vector_type(4)));
typedef __bf16 bf16x8 __attribute__((ext_vector_type(8)));
typedef unsigned short us8 __attribute__((ext_vector_type(8)));
typedef unsigned short us4 __attribute__((ext_vector_type(4)));
typedef float  f32x4v __attribute__((ext_vector_type(4)));
typedef unsigned int u32x2 __attribute__((ext_vector_type(2)));

#define AS1 __attribute__((address_space(1)))
#define AS3 __attribute__((address_space(3)))

// fp32 -> bf16 round-to-nearest-even (scalar)
__device__ __forceinline__ u16 f2b(float f) {
  unsigned u = __float_as_uint(f);
  u += 0x7FFFu + ((u >> 16) & 1u);
  return (u16)(u >> 16);
}

// pack two fp32 -> bf16x2 dword (round-half-up; a = low 16, b = high 16)
__device__ __forceinline__ unsigned pkbf(float a, float b) {
  unsigned ua = __float_as_uint(a) + 0x8000u;
  unsigned ub = __float_as_uint(b) + 0x8000u;
  return __builtin_amdgcn_perm(ub, ua, 0x07060302u);
}

// pack two fp32 -> bf16x2 via casts (compiler emits v_cvt_pk_bf16_f32, RNE)
__device__ __forceinline__ unsigned cvtpk(float a, float b) {
  unsigned short lo = __builtin_bit_cast(unsigned short, (__bf16)a);
  unsigned short hi = __builtin_bit_cast(unsigned short, (__bf16)b);
  return (unsigned)lo | ((unsigned)hi << 16);
}

__device__ __forceinline__ bf16x8 ldfrag(const u16* p) {
  us8 v = *(const us8*)p;
  return __builtin_bit_cast(bf16x8, v);
}

__device__ __forceinline__ f32x4 mfma16(bf16x8 a, bf16x8 b, f32x4 c) {
  return __builtin_amdgcn_mfma_f32_16x16x32_bf16(a, b, c, 0, 0, 0);
}

// async global->LDS, 16B per lane; lds base must be wave-uniform (lane*16 auto-added)
__device__ __forceinline__ void gl_lds16(const u16* g, AS3 u16* l) {
  __builtin_amdgcn_global_load_lds((AS1 void*)g, (AS3 void*)l, 16, 0, 0);
}

// R13 BK=64 LDS layout: rows of 64 u16 = eight 16B granules; row stride 128B
// = exactly 32 banks, so bank depends only on granule position. Swizzle:
//   LDS[row r][pos p] = global[r][g], p = g ^ (r&7)
// Staging (linear dest, global_load_lds): source granule g = (lane&7)^(lane>>3).
// Reader frag (row R, kchunk kk, quad): pos = (kk*4+quad) ^ (R&7), R&7=l16&7.
// Every 8 consecutive lanes covers pos 0..7 bijectively -> ~0 conflicts.
// R18: GEMMs reverted to R15's serial-stage loop — R16/R17 dbuf variants both
// lost to it (at 2 blocks/CU, inter-block TLP already anti-phases drain vs
// compute, m114; dbuf only added addressing VALU).

// ---- fused cast: x + all 4 weights. grid-stride, 3072 blocks x 4 iters ----
__global__ __launch_bounds__(256) void cvt_all(
    const float* __restrict__ x,
    const float* __restrict__ Wq, const float* __restrict__ Wk,
    const float* __restrict__ Wv, const float* __restrict__ Wo,
    u16* __restrict__ xb, u16* __restrict__ Wqkv, u16* __restrict__ Wob) {
  for (int blk = blockIdx.x; blk < 12288; blk += 3072) {
    const float* s;
    u16* d;
    int i;
    if (blk < 8192)       { s = x;  d = xb;             i = blk * 256 + threadIdx.x; }
    else if (blk < 9216)  { s = Wq; d = Wqkv;           i = (blk - 8192) * 256 + threadIdx.x; }
    else if (blk < 10240) { s = Wk; d = Wqkv + 1048576; i = (blk - 9216) * 256 + threadIdx.x; }
    else if (blk < 11264) { s = Wv; d = Wqkv + 2097152; i = (blk - 10240) * 256 + threadIdx.x; }
    else                  { s = Wo; d = Wob;            i = (blk - 11264) * 256 + threadIdx.x; }
    f32x4v f = ((const f32x4v*)s)[i];
    us4 o = { f2b(f[0]), f2b(f[1]), f2b(f[2]), f2b(f[3]) };
    ((us4*)d)[i] = o;
  }
}

// ---- GEMM1: C = X @ Wqkv^T -> Q (prescaled by 0.125*log2e), K, Vt.
// 128x128 tile, 256 threads, BK=64 (R13), per-section MFMA orientation +
// 8B packed epilogue (R12), persistent 512-block grid + same-A sec fusion +
// XCD-chunk swizzle (R15). Serial-stage 2-barrier K-loop (R15; best measured
// 68.7 us — R16/R17 pipelining variants regressed).
__global__ __launch_bounds__(256) void gemm_qkv(
    const u16* __restrict__ A, const u16* __restrict__ W,
    u16* __restrict__ Qb, u16* __restrict__ Kb, u16* __restrict__ Vt) {
  __shared__ u16 lA[128 * 64];   // 16 KB
  __shared__ u16 lB[128 * 64];   // 16 KB
  const int tid = threadIdx.x;
  const int lane = tid & 63, wave = tid >> 6;
  const int quad = lane >> 4, l16 = lane & 15;
  const int wr = wave >> 1, wc = wave & 1;

  const int p = blockIdx.x;
  const int l = (p & 7) * 64 + (p >> 3);   // XCD-chunk swizzle (bijective)
  const int by = l >> 3;
  const int bx0 = l & 7;
  const int m0 = by * 128;

  AS3 u16* lA3 = (AS3 u16*)lA;
  AS3 u16* lB3 = (AS3 u16*)lB;
  const int g3 = (((lane & 7) ^ (lane >> 3)) * 8);   // staging source granule col
  const int srow = lane >> 3;                        // 0..7 within 8-row group
  const int pA = ((quad) ^ (l16 & 7)) * 8;           // reader pos, kk=0
  const int pB = ((4 + quad) ^ (l16 & 7)) * 8;       // reader pos, kk=1

  const u16* gA = A + (size_t)(m0 + wave * 8 + srow) * 1024 + g3;

#pragma unroll 1
  for (int sec = 0; sec < 3; sec++) {    // tile bx = bx0 + sec*8; sec: 0=Q 1=K 2=V
    const int n0 = (bx0 + sec * 8) * 128;
    const u16* gB = W + (size_t)(n0 + wave * 8 + srow) * 1024 + g3;
    f32x4 acc[4][4] = {};

    for (int k0 = 0; k0 < 1024; k0 += 64) {
      __syncthreads();
#pragma unroll
      for (int i = 0; i < 4; i++) {   // instruction j = i*4+wave stages rows j*8..j*8+7
        gl_lds16(gA + (size_t)i * 32768 + k0, lA3 + (i * 4 + wave) * 512);
        gl_lds16(gB + (size_t)i * 32768 + k0, lB3 + (i * 4 + wave) * 512);
      }
      __syncthreads();
#pragma unroll
      for (int kk = 0; kk < 2; kk++) {
        const int pk = kk ? pB : pA;
        bf16x8 aF[4], bF[4];
#pragma unroll
        for (int mt = 0; mt < 4; mt++)
          aF[mt] = ldfrag(&lA[(wr * 64 + mt * 16 + l16) * 64 + pk]);
#pragma unroll
        for (int nt = 0; nt < 4; nt++)
          bF[nt] = ldfrag(&lB[(wc * 64 + nt * 16 + l16) * 64 + pk]);
        if (sec != 2) {  // SWAPPED: D[row=feature n, col=token m]
#pragma unroll
          for (int mt = 0; mt < 4; mt++)
#pragma unroll
            for (int nt = 0; nt < 4; nt++)
              acc[mt][nt] = mfma16(bF[nt], aF[mt], acc[mt][nt]);
        } else {         // NON-swapped: D[row=token m, col=feature n]
#pragma unroll
          for (int mt = 0; mt < 4; mt++)
#pragma unroll
            for (int nt = 0; nt < 4; nt++)
              acc[mt][nt] = mfma16(aF[mt], bF[nt], acc[mt][nt]);
        }
      }
    }

    if (sec != 2) {
      // Q/K: regs walk e; lane l16 = token. 8B store per (mt,nt).
      const float qsc = (sec == 0) ? 0.180336880111120426f : 1.0f;  // 0.125*log2e
      u16* __restrict__ D = (sec == 0) ? Qb : Kb;
      const int hb = ((n0 & 1023) >> 6) + wc;  // head (uniform per wave-col)
#pragma unroll
      for (int mt = 0; mt < 4; mt++) {
        int t = m0 + wr * 64 + mt * 16 + l16;
        int b = t >> 11, tt = t & 2047;
        size_t rowb = (((size_t)b * 16 + hb) * 2048 + tt) * 64;
#pragma unroll
        for (int nt = 0; nt < 4; nt++) {
          int e = nt * 16 + quad * 4;
          u32x2 pk = { pkbf(acc[mt][nt][0] * qsc, acc[mt][nt][1] * qsc),
                       pkbf(acc[mt][nt][2] * qsc, acc[mt][nt][3] * qsc) };
          *(u32x2*)&D[rowb + e] = pk;
        }
      }
    } else {
      // V: regs walk t; lane l16 = feature. 8B store per (mt,nt).
#pragma unroll
      for (int mt = 0; mt < 4; mt++) {
        int t = m0 + wr * 64 + mt * 16 + quad * 4;
        int b = t >> 11, tt = t & 2047;
#pragma unroll
        for (int nt = 0; nt < 4; nt++) {
          int ns = (n0 & 1023) + wc * 64 + nt * 16 + l16;
          int h = ns >> 6, e = ns & 63;
          size_t addr = (((size_t)b * 16 + h) * 64 + e) * 2048 + tt;
          u32x2 pk = { pkbf(acc[mt][nt][0], acc[mt][nt][1]),
                       pkbf(acc[mt][nt][2], acc[mt][nt][3]) };
          *(u32x2*)&Vt[addr] = pk;
        }
      }
    }
  }
}

// ---- flash attention v5: transposed S (A=K, B=Q); paired Q-tiles.
// grid (bh=64, pair=8), block 512 (8 waves).
// R14: max-free softmax (S bounded, exp2 domain); K/V via global_load_lds
// with XOR-granule swizzle; cvt_pk packing; l-sum on the MFMA pipe (R11).
// R18: KVBLK 128 -> 256 — barrier pairs per block 17 -> 9 (uniform:
// (qb+2)/2 + (17-qb)/2 = 9), halving stage/drain events. Compute runs the
// two 128-halves sequentially (S[8] live at a time, VGPR flat); fully-masked
// halves skipped by wave-uniform s0h > t0 test, so active compute is
// unchanged (17 halves/pair). LDS 75 KB -> still 2 blocks/CU.
__global__ __launch_bounds__(512, 4) void attn(
    const u16* __restrict__ Q, const u16* __restrict__ K,
    const u16* __restrict__ Vt, u16* __restrict__ O) {
  __shared__ u16 lK[256 * 64];     // [s][e-swz] 32 KB
  __shared__ u16 lV[64 * 256];     // [e][s-swz] 32 KB
  __shared__ u16 lP[8 * 16 * 40];  // per-wave [16t][32s, stride 40]
  const int tid = threadIdx.x;
  const int lane = tid & 63, wave = tid >> 6;
  const int quad = lane >> 4, l16 = lane & 15;
  const int bh = blockIdx.x;
  const int pidx = blockIdx.y;     // 0..7
  const size_t base = (size_t)bh * (2048 * 64);
  u16* lPw = lP + wave * 640;
  const int b = bh >> 4, h = bh & 15;
  AS3 u16* lK3 = (AS3 u16*)lK;
  AS3 u16* lV3 = (AS3 u16*)lV;

  // K staging (256x64): instr i stages rows i*64 + (tid>>3); src granule
  // g = (tid&7)^((tid>>3)&7); dest granule i*512 + tid (linear).
  const int g3 = ((lane & 7) ^ (lane >> 3)) * 8;
  const u16* gK0 = K + base + (size_t)(tid >> 3) * 64 + g3;
  // V staging (64x256, 32 granules/row): instr i stages rows i*16 + (tid>>5);
  // src granule g = (tid&31) ^ ((tid>>5)&7); dest granule i*512 + tid.
  const int gcV = (((tid & 31) ^ ((tid >> 5) & 7)) * 8);
  const u16* gV0 = Vt + base + (size_t)(tid >> 5) * 2048 + gcV;

  const int e7 = l16 & 7;
  const int pq0 = (quad ^ e7) * 8;        // K read pos, e-granule quad
  const int pq1 = ((4 + quad) ^ e7) * 8;  // K read pos, e-granule 4+quad

  // ones A-frag for the l-sum MFMA (bf16 1.0 = 0x3F80)
  us8 ones_u = { 0x3F80, 0x3F80, 0x3F80, 0x3F80, 0x3F80, 0x3F80, 0x3F80, 0x3F80 };
  const bf16x8 onesA = __builtin_bit_cast(bf16x8, ones_u);

  for (int half = 0; half < 2; half++) {
    const int qb = half ? pidx : (15 - pidx);   // long tile first
    const int t0 = qb << 7;
    const int tq = t0 + wave * 16 + l16;
    const bf16x8 qF0 = ldfrag(Q + base + (size_t)tq * 64 + quad * 8);
    const bf16x8 qF1 = ldfrag(Q + base + (size_t)tq * 64 + 32 + quad * 8);
    float l_i = 0.f;
    f32x4 o[4] = {};
    const int niter = (qb + 2) >> 1;

    for (int j = 0; j < niter; j++) {
      const int s0 = j << 8;
      __syncthreads();
#pragma unroll
      for (int i = 0; i < 4; i++) {
        gl_lds16(gK0 + (size_t)(s0 + i * 64) * 64, lK3 + i * 4096 + wave * 512);
        gl_lds16(gV0 + (size_t)i * 32768 + s0,     lV3 + i * 4096 + wave * 512);
      }
      __syncthreads();

#pragma unroll
      for (int hh = 0; hh < 2; hh++) {
        const int s0h = s0 + hh * 128;
        if (s0h > t0) break;            // wave-uniform: fully-masked half

        // S^T = K·Q^T : lane owns col t=tq, rows s = s0h + nt*16+quad*4+r
        f32x4 S[8];
        __builtin_amdgcn_s_setprio(1);
#pragma unroll
        for (int nt = 0; nt < 8; nt++) {
          int sr = hh * 128 + nt * 16 + l16;
          f32x4 a = {};
          a = mfma16(ldfrag(&lK[sr * 64 + pq0]), qF0, a);
          a = mfma16(ldfrag(&lK[sr * 64 + pq1]), qF1, a);
          S[nt] = a;
        }
        __builtin_amdgcn_s_setprio(0);

        if (s0h == t0) {  // causal mask on diagonal half
#pragma unroll
          for (int nt = 0; nt < 8; nt++)
#pragma unroll
            for (int r = 0; r < 4; r++) {
              int s = s0h + nt * 16 + quad * 4 + r;
              if (s > tq) S[nt][r] = -INFINITY;
            }
        }

        // shift-free softmax numerator: P = exp2(S) (S bounded; exp2(-inf)=0)
#pragma unroll
        for (int nt = 0; nt < 8; nt++)
#pragma unroll
          for (int r = 0; r < 4; r++)
            S[nt][r] = __builtin_amdgcn_exp2f(S[nt][r]);

        // PV per 32-wide s-chunk: P^T through wave-private LDS (in-order DS).
        f32x4 ol = {};
#pragma unroll
        for (int c = 0; c < 4; c++) {
          u32x2 d0 = { cvtpk(S[2*c][0],   S[2*c][1]),   cvtpk(S[2*c][2],   S[2*c][3]) };
          u32x2 d1 = { cvtpk(S[2*c+1][0], S[2*c+1][1]), cvtpk(S[2*c+1][2], S[2*c+1][3]) };
          *(u32x2*)&lPw[l16 * 40 + quad * 4]      = d0;  // s_local = quad*4+r
          *(u32x2*)&lPw[l16 * 40 + 16 + quad * 4] = d1;  // s_local = 16+quad*4+r
          __asm__ volatile("s_waitcnt lgkmcnt(0)" ::: "memory");
          bf16x8 bP = ldfrag(&lPw[l16 * 40 + quad * 8]);  // B-frag: n=t=l16, k=quad*8+j
          __builtin_amdgcn_s_setprio(1);
#pragma unroll
          for (int ot = 0; ot < 4; ot++) {
            int pos = ((hh * 16 + c * 4 + quad) ^ e7) * 8;  // V s-granule
            o[ot] = mfma16(ldfrag(&lV[(ot * 16 + l16) * 256 + pos]), bP, o[ot]);
          }
          ol = mfma16(onesA, bP, ol);
          __builtin_amdgcn_s_setprio(0);
        }
        l_i += ol[0];
      }
    }

    // O^T in C-layout: row e = ot*16+quad*4+r, col t = l16 -> per-lane 8B stores
    const float inv = 1.f / l_i;
#pragma unroll
    for (int ot = 0; ot < 4; ot++) {
      u32x2 pk = { cvtpk(o[ot][0] * inv, o[ot][1] * inv),
                   cvtpk(o[ot][2] * inv, o[ot][3] * inv) };
      *(u32x2*)&O[((size_t)b * 2048 + tq) * 1024 + h * 64 + ot * 16 + quad * 4] = pk;
    }
  }
}

// ---- GEMM2: out = Ao @ Wo^T + bo, fp32 epilogue. BK=64 serial (R13/R15).
// grid (8, 64), block 256.
__global__ __launch_bounds__(256) void gemm_out(
    const u16* __restrict__ A, const u16* __restrict__ W,
    const float* __restrict__ bias, float* __restrict__ out) {
  __shared__ u16 lA[128 * 64];
  __shared__ u16 lB[128 * 64];
  const int tid = threadIdx.x;
  const int lane = tid & 63, wave = tid >> 6;
  const int quad = lane >> 4, l16 = lane & 15;
  const int wr = wave >> 1, wc = wave & 1;
  const int m0 = blockIdx.y * 128;
  const int n0 = blockIdx.x * 128;
  AS3 u16* lA3 = (AS3 u16*)lA;
  AS3 u16* lB3 = (AS3 u16*)lB;
  f32x4 acc[4][4] = {};
  const int g3 = (((lane & 7) ^ (lane >> 3)) * 8);
  const int srow = lane >> 3;
  const int pA = ((quad) ^ (l16 & 7)) * 8;
  const int pB = ((4 + quad) ^ (l16 & 7)) * 8;
  const u16* gA = A + (size_t)(m0 + wave * 8 + srow) * 1024 + g3;
  const u16* gB = W + (size_t)(n0 + wave * 8 + srow) * 1024 + g3;

  for (int k0 = 0; k0 < 1024; k0 += 64) {
    __syncthreads();
#pragma unroll
    for (int i = 0; i < 4; i++) {
      gl_lds16(gA + (size_t)i * 32768 + k0, lA3 + (i * 4 + wave) * 512);
      gl_lds16(gB + (size_t)i * 32768 + k0, lB3 + (i * 4 + wave) * 512);
    }
    __syncthreads();
#pragma unroll
    for (int kk = 0; kk < 2; kk++) {
      const int pk = kk ? pB : pA;
      bf16x8 aF[4], bF[4];
#pragma unroll
      for (int mt = 0; mt < 4; mt++)
        aF[mt] = ldfrag(&lA[(wr * 64 + mt * 16 + l16) * 64 + pk]);
#pragma unroll
      for (int nt = 0; nt < 4; nt++)
        bF[nt] = ldfrag(&lB[(wc * 64 + nt * 16 + l16) * 64 + pk]);
#pragma unroll
      for (int mt = 0; mt < 4; mt++)
#pragma unroll
        for (int nt = 0; nt < 4; nt++)
          acc[mt][nt] = mfma16(aF[mt], bF[nt], acc[mt][nt]);
    }
  }

#pragma unroll
  for (int mt = 0; mt < 4; mt++) {
#pragma unroll
    for (int nt = 0; nt < 4; nt++) {
#pragma unroll
      for (int r = 0; r < 4; r++) {
        int m = m0 + wr * 64 + mt * 16 + quad * 4 + r;
        int n = n0 + wc * 64 + nt * 16 + l16;
        out[(size_t)m * 1024 + n] = acc[mt][nt][r] + bias[n];
      }
    }
  }
}

extern "C" void kernel_launch(void* const* d_in, const int* in_sizes, int n_in,
                              void* d_out, int out_size, void* d_ws, size_t ws_size,
                              hipStream_t stream) {
  const float* x  = (const float*)d_in[0];
  const float* Wq = (const float*)d_in[1];
  const float* Wk = (const float*)d_in[2];
  const float* Wv = (const float*)d_in[3];
  const float* Wo = (const float*)d_in[4];
  const float* bo = (const float*)d_in[5];
  float* out = (float*)d_out;

  // ws (u16 elems), 40 MB total: xb/Ao | Wqkv | Wob | Qb.
  // d_out doubles as scratch for Kb+Vt (dead before gemm_out's fp32 write).
  u16* ws   = (u16*)d_ws;
  u16* xb   = ws;
  u16* Wqkv = ws + 8388608;
  u16* Wob  = ws + 11534336;
  u16* Qb   = ws + 12582912;
  u16* Ao   = xb;                       // lifetime-disjoint reuse
  u16* Kb   = (u16*)d_out;
  u16* Vt   = Kb + 8388608;

  cvt_all<<<3072, 256, 0, stream>>>(x, Wq, Wk, Wv, Wo, xb, Wqkv, Wob);
  gemm_qkv<<<512, 256, 0, stream>>>(xb, Wqkv, Qb, Kb, Vt);
  attn<<<dim3(64, 8), 512, 0, stream>>>(Qb, Kb, Vt, Ao);
  gemm_out<<<dim3(8, 64), 256, 0, stream>>>(Ao, Wob, bo, out);
}